// Round 3
// baseline (115.424 us; speedup 1.0000x reference)
//
#include <hip/hip_runtime.h>
#include <hip/hip_bf16.h>
#include <math.h>

// Problem constants (fixed by setup_inputs): B=128, P=4096, L=128
#define BB 128
#define PP 4096
#define LL 128
#define BLOCK 256
#define PROPS 2                       // proposals per thread
#define CHUNKS (PP / (BLOCK * PROPS)) // 8 chunks per batch
#define SCALE 32.0f

__global__ __launch_bounds__(BLOCK) void classifier_loss_kernel(
    const float* __restrict__ cls,     // [B, 2P]
    const float* __restrict__ bbox,    // [B, 4P]
    const float* __restrict__ roi,     // [B, P, 4]
    const float* __restrict__ labels,  // [B, L, 4]
    const int* __restrict__ neg_enabled,
    float* __restrict__ out)
{
    __shared__ float s_red[BLOCK / 64];

    const int b     = blockIdx.x >> 3;       // / CHUNKS
    const int chunk = blockIdx.x & (CHUNKS - 1);
    const int pbase = chunk * (BLOCK * PROPS) + threadIdx.x;

    // Wave-uniform label base pointer -> scalar (s_load) accesses in the loop
    const float* __restrict__ lab = labels + (size_t)b * LL * 4;

    // Per-proposal state
    float rx[PROPS], ry[PROPS], rx2[PROPS], ry2[PROPS], rarea[PROPS];
    float bi[PROPS], bd[PROPS];   // best inter, best denom (= S_l + R)
    int   bidx[PROPS];

    #pragma unroll
    for (int j = 0; j < PROPS; ++j) {
        const int p = pbase + j * BLOCK;
        const float* rp = roi + ((size_t)b * PP + p) * 4;
        rx[j]  = rp[0] * SCALE;
        ry[j]  = rp[1] * SCALE;
        float rw = rp[2] * SCALE, rh = rp[3] * SCALE;
        rx2[j] = rx[j] + rw;
        ry2[j] = ry[j] + rh;
        rarea[j] = rw * rh;
        // init so that label 0 always wins the first comparison
        bi[j] = -1.0f;
        bd[j] = 1.0f;
        bidx[j] = 0;
    }

    // --- argmax IoU over labels ---
    // iou_i = I/(S_i + R - I); c_i = iou/(1+iou) = I/(S_i + R) is monotone in
    // iou, so argmax c == argmax iou. Compare c cross-multiplied (denoms > 0):
    //   inter*bd > bi*denom  <=>  c_new > c_best.  Strict '>' keeps first max.
    #pragma unroll 4
    for (int li = 0; li < LL; ++li) {
        const float lx = lab[li * 4 + 0];
        const float ly = lab[li * 4 + 1];
        const float lw = lab[li * 4 + 2];
        const float lh = lab[li * 4 + 3];
        const float x2 = lx + lw;
        const float y2 = ly + lh;
        const float area = lw * lh;
        #pragma unroll
        for (int j = 0; j < PROPS; ++j) {
            float ix = fmaxf(0.0f, fminf(x2, rx2[j]) - fmaxf(lx, rx[j]));
            float iy = fmaxf(0.0f, fminf(y2, ry2[j]) - fmaxf(ly, ry[j]));
            float inter = ix * iy;
            float denom = area + rarea[j];
            bool gt = inter * bd[j] > bi[j] * denom;
            bi[j]   = gt ? inter : bi[j];
            bd[j]   = gt ? denom : bd[j];
            bidx[j] = gt ? li    : bidx[j];
        }
    }

    const float LOG01 = -2.3025850929940457f;  // log(0.1)
    const float LOG09 = -0.10536051565782628f; // log(0.9)
    const bool neg_on = neg_enabled[0] > 0;

    float acc = 0.0f;
    #pragma unroll
    for (int j = 0; j < PROPS; ++j) {
        const int p = pbase + j * BLOCK;
        const bool pos = (bi[j] > 0.0f) && (bidx[j] > 0);  // any_hit && match>0

        // classification CE (softmax over 2 classes)
        const float s0 = cls[(size_t)b * 2 * PP + p];
        const float s1 = cls[(size_t)b * 2 * PP + PP + p];
        const float mx = fmaxf(s0, s1);
        const float e0 = expf(s0 - mx);
        const float e1 = expf(s1 - mx);
        const float inv = 1.0f / (e0 + e1);
        const float p0 = e0 * inv, p1 = e1 * inv;
        const float ce_pos = -(p0 * LOG01 + p1 * LOG09);
        const float ce_neg = -(p0 * LOG09 + p1 * LOG01);

        float per;
        if (pos) {
            const float* mp = lab + bidx[j] * 4;   // per-lane gather, rare path
            float mxl = mp[0], myl = mp[1], mwl = mp[2], mhl = mp[3];
            float rw = rx2[j] - rx[j];
            float rh = ry2[j] - ry[j];
            float tx = (mxl - rx[j]) / rw;
            float ty = (myl - ry[j]) / rh;
            float tw = logf(fmaxf(mwl / rw, 1e-8f));
            float th = logf(fmaxf(mhl / rh, 1e-8f));
            const float* bp = bbox + (size_t)b * 4 * PP + p;
            float ex = tx - bp[0];
            float ey = ty - bp[PP];
            float ew = tw - bp[2 * PP];
            float eh = th - bp[3 * PP];
            float ax = fabsf(ex), ay = fabsf(ey), aw = fabsf(ew), ah = fabsf(eh);
            float hx = (ax <= 1.0f) ? 0.5f * ex * ex : ax - 0.5f;
            float hy = (ay <= 1.0f) ? 0.5f * ey * ey : ay - 0.5f;
            float hw = (aw <= 1.0f) ? 0.5f * ew * ew : aw - 0.5f;
            float hh = (ah <= 1.0f) ? 0.5f * eh * eh : ah - 0.5f;
            float huber = 0.25f * (hx + hy + hw + hh);
            per = 2.0f * huber + ce_pos;
        } else {
            per = neg_on ? ce_neg : 0.0f;
        }
        acc += per;
    }

    // --- reduce: wave64 shuffle -> LDS -> one atomic per block ---
    float v = acc;
    #pragma unroll
    for (int off = 32; off > 0; off >>= 1)
        v += __shfl_down(v, off, 64);
    if ((threadIdx.x & 63) == 0)
        s_red[threadIdx.x >> 6] = v;
    __syncthreads();
    if (threadIdx.x == 0) {
        float blk = s_red[0] + s_red[1] + s_red[2] + s_red[3];
        atomicAdd(out, blk);
    }
}

extern "C" void kernel_launch(void* const* d_in, const int* in_sizes, int n_in,
                              void* d_out, int out_size, void* d_ws, size_t ws_size,
                              hipStream_t stream) {
    const float* cls    = (const float*)d_in[0];
    const float* bbox   = (const float*)d_in[1];
    const float* roi    = (const float*)d_in[2];
    const float* labels = (const float*)d_in[3];
    const int*   neg    = (const int*)d_in[4];
    float* out = (float*)d_out;

    hipMemsetAsync(out, 0, sizeof(float) * out_size, stream);
    classifier_loss_kernel<<<dim3(BB * CHUNKS), dim3(BLOCK), 0, stream>>>(
        cls, bbox, roi, labels, neg, out);
}

// Round 4
// 109.081 us; speedup vs baseline: 1.0581x; 1.0581x over previous
//
#include <hip/hip_runtime.h>
#include <hip/hip_bf16.h>
#include <math.h>

// Problem constants (fixed by setup_inputs): B=128, P=4096, L=128
#define BB 128
#define PP 4096
#define LL 128
#define BLOCK 256
#define CHUNKS (PP / BLOCK)   // 16 blocks per batch -> 2048 blocks, 8192 waves
#define SCALE 32.0f
#define LCHUNK 8              // labels per scalar-load batch

__global__ __launch_bounds__(BLOCK) void classifier_loss_kernel(
    const float* __restrict__ cls,     // [B, 2P]
    const float* __restrict__ bbox,    // [B, 4P]
    const float* __restrict__ roi,     // [B, P, 4]
    const float* __restrict__ labels,  // [B, L, 4]
    const int* __restrict__ neg_enabled,
    float* __restrict__ out)
{
    __shared__ float s_red[BLOCK / 64];

    const int b     = blockIdx.x >> 4;          // / CHUNKS
    const int chunk = blockIdx.x & (CHUNKS - 1);
    const int p     = chunk * BLOCK + threadIdx.x;

    // Wave-uniform label base pointer -> scalar (s_load) accesses in the loop
    const float* __restrict__ lab = labels + (size_t)b * LL * 4;

    // Proposal box in image coords
    const float* rp = roi + ((size_t)b * PP + p) * 4;
    const float rx = rp[0] * SCALE, ry = rp[1] * SCALE;
    const float rw = rp[2] * SCALE, rh = rp[3] * SCALE;
    const float rx2 = rx + rw, ry2 = ry + rh;
    const float rarea = rw * rh;

    // --- argmax IoU over labels, division-free ---
    // c_i = inter/(S_i + R) = iou/(1+iou) is monotone in iou -> same argmax.
    // Compare cross-multiplied (denoms > 0): inter*bd > bi*denom.
    // Init bi=-1, bd=1 so label 0 always wins the first strict compare.
    float best_inter = -1.0f, best_denom = 1.0f;
    int   best_idx = 0;

    for (int lc = 0; lc < LL; lc += LCHUNK) {
        // Batch the wave-uniform label reads so the compiler can emit wide
        // s_load_dwordx16 blocks up front and overlap K$ latency.
        float lv[LCHUNK * 4];
        #pragma unroll
        for (int k = 0; k < LCHUNK * 4; ++k)
            lv[k] = lab[lc * 4 + k];

        #pragma unroll
        for (int u = 0; u < LCHUNK; ++u) {
            const float lx = lv[u * 4 + 0];
            const float ly = lv[u * 4 + 1];
            const float lw = lv[u * 4 + 2];
            const float lh = lv[u * 4 + 3];
            const float x2 = lx + lw;        // scalar ALU (uniform)
            const float y2 = ly + lh;
            const float area = lw * lh;
            float ix = fmaxf(0.0f, fminf(x2, rx2) - fmaxf(lx, rx));
            float iy = fmaxf(0.0f, fminf(y2, ry2) - fmaxf(ly, ry));
            float inter = ix * iy;
            float denom = area + rarea;
            bool gt = inter * best_denom > best_inter * denom;
            best_inter = gt ? inter : best_inter;
            best_denom = gt ? denom : best_denom;
            best_idx   = gt ? (lc + u) : best_idx;
        }
    }

    const bool pos = (best_inter > 0.0f) && (best_idx > 0);  // any_hit && match>0

    // --- classification CE (softmax over 2 classes) ---
    const float s0 = cls[(size_t)b * 2 * PP + p];
    const float s1 = cls[(size_t)b * 2 * PP + PP + p];
    const float mx = fmaxf(s0, s1);
    const float e0 = expf(s0 - mx);
    const float e1 = expf(s1 - mx);
    const float inv = 1.0f / (e0 + e1);
    const float p0 = e0 * inv, p1 = e1 * inv;
    const float LOG01 = -2.3025850929940457f;  // log(0.1)
    const float LOG09 = -0.10536051565782628f; // log(0.9)
    const float ce_pos = -(p0 * LOG01 + p1 * LOG09);
    const float ce_neg = -(p0 * LOG09 + p1 * LOG01);

    float per;
    if (pos) {
        const float* mp = lab + best_idx * 4;   // divergent gather, rare path
        float mxl = mp[0], myl = mp[1], mwl = mp[2], mhl = mp[3];
        float tx = (mxl - rx) / rw;
        float ty = (myl - ry) / rh;
        float tw = logf(fmaxf(mwl / rw, 1e-8f));
        float th = logf(fmaxf(mhl / rh, 1e-8f));
        const float* bp = bbox + (size_t)b * 4 * PP + p;
        float ex = tx - bp[0];
        float ey = ty - bp[PP];
        float ew = tw - bp[2 * PP];
        float eh = th - bp[3 * PP];
        float ax = fabsf(ex), ay = fabsf(ey), aw = fabsf(ew), ah = fabsf(eh);
        float hx = (ax <= 1.0f) ? 0.5f * ex * ex : ax - 0.5f;
        float hy = (ay <= 1.0f) ? 0.5f * ey * ey : ay - 0.5f;
        float hw = (aw <= 1.0f) ? 0.5f * ew * ew : aw - 0.5f;
        float hh = (ah <= 1.0f) ? 0.5f * eh * eh : ah - 0.5f;
        float huber = 0.25f * (hx + hy + hw + hh);
        per = 2.0f * huber + ce_pos;
    } else {
        per = (neg_enabled[0] > 0) ? ce_neg : 0.0f;
    }

    // --- reduce: wave64 shuffle -> LDS -> one atomic per block ---
    float v = per;
    #pragma unroll
    for (int off = 32; off > 0; off >>= 1)
        v += __shfl_down(v, off, 64);
    if ((threadIdx.x & 63) == 0)
        s_red[threadIdx.x >> 6] = v;
    __syncthreads();
    if (threadIdx.x == 0) {
        float blk = s_red[0] + s_red[1] + s_red[2] + s_red[3];
        atomicAdd(out, blk);
    }
}

extern "C" void kernel_launch(void* const* d_in, const int* in_sizes, int n_in,
                              void* d_out, int out_size, void* d_ws, size_t ws_size,
                              hipStream_t stream) {
    const float* cls    = (const float*)d_in[0];
    const float* bbox   = (const float*)d_in[1];
    const float* roi    = (const float*)d_in[2];
    const float* labels = (const float*)d_in[3];
    const int*   neg    = (const int*)d_in[4];
    float* out = (float*)d_out;

    hipMemsetAsync(out, 0, sizeof(float) * out_size, stream);
    classifier_loss_kernel<<<dim3(BB * CHUNKS), dim3(BLOCK), 0, stream>>>(
        cls, bbox, roi, labels, neg, out);
}